// Round 1
// baseline (118.914 us; speedup 1.0000x reference)
//
#include <hip/hip_runtime.h>
#include <hip/hip_bf16.h>

typedef __attribute__((ext_vector_type(8))) short short8;
typedef __attribute__((ext_vector_type(4))) float float4v;

#define T_LEN 4096
#define L_LEN 128
#define NWIN  3969
#define CK    128
#define W_BLK 128
#define NCHUNK 32
#define NEG_INF (-3.402823466e38f)

__device__ __forceinline__ unsigned short f2bf(float f) {
    unsigned int u = __float_as_uint(f);
    u += 0x7fffu + ((u >> 16) & 1u);          // RNE
    return (unsigned short)(u >> 16);
}
__device__ __forceinline__ float bf2f(unsigned short b) {
    return __uint_as_float(((unsigned int)b) << 16);
}
// order-preserving float->uint encoding (max-compatible)
__device__ __forceinline__ unsigned enc_f(float f) {
    unsigned i = __float_as_uint(f);
    return (i & 0x80000000u) ? ~i : (i | 0x80000000u);
}
__device__ __forceinline__ float dec_f(unsigned e) {
    return (e & 0x80000000u) ? __uint_as_float(e & 0x7fffffffu)
                             : __uint_as_float(~e);
}

// grid 256 x 128 threads: blocks 0..127 init d_out encoding; blocks 128..255
// normalize shapelet ck=blockIdx-128 and write B-fragment-swizzled bf16 + sum.
__global__ void prep_init(const float* __restrict__ sh,
                          unsigned short* __restrict__ wsB,
                          float* __restrict__ csum,
                          unsigned* __restrict__ oenc) {
    const int t = threadIdx.x;           // 128 threads
    if (blockIdx.x < 128) {
        oenc[blockIdx.x * 256 + t]       = 0u;   // enc floor (< any finite enc)
        oenc[blockIdx.x * 256 + 128 + t] = 0u;
        return;
    }
    const int ck = blockIdx.x - 128;     // shapelet index 0..127
    const int l  = t;                    // element 0..127
    __shared__ float rs[2], rq[2], rc[2];
    const int lane = t & 63, wv = t >> 6;

    float v = sh[ck * L_LEN + l];
    float s = v, q = v * v;
    #pragma unroll
    for (int off = 32; off >= 1; off >>= 1) {
        s += __shfl_xor(s, off);
        q += __shfl_xor(q, off);
    }
    if (lane == 0) { rs[wv] = s; rq[wv] = q; }
    __syncthreads();
    float sm = rs[0] + rs[1], sq = rq[0] + rq[1];
    float mu  = sm * (1.f / L_LEN);
    float var = fmaxf(sq * (1.f / L_LEN) - mu * mu, 0.f);
    float inv = 1.f / (sqrtf(var) + 1e-6f);

    unsigned short b = f2bf((v - mu) * inv);
    // swizzle to B-operand fragment order: lane' = q*16 + n, 8 contiguous bf16
    const int nt = ck >> 4, n = ck & 15;
    const int kt = l >> 5, qd = (l >> 3) & 3, jj = l & 7;
    wsB[((((nt * 4 + kt) * 64) + qd * 16 + n) << 3) + jj] = b;

    // sum of bf16-rounded s_norm (epilogue correction term)
    float cv = bf2f(b);
    #pragma unroll
    for (int off = 32; off >= 1; off >>= 1) cv += __shfl_xor(cv, off);
    if (lane == 0) rc[wv] = cv;
    __syncthreads();
    if (t == 0) csum[ck] = rc[0] + rc[1];
}

// main: one block = one (row, 128-window chunk); 4 waves.
// wave w: nhalf = w&1 (64 shapelets), mgroup = w>>1 (4 m-tiles).
// m-tile j covers windows T0 + j + 8m (m=0..15)  -> all A-frags 16B aligned
// in shifted copy j.
__global__ __launch_bounds__(256, 2)
void conv_main(const float* __restrict__ x,
               const unsigned short* __restrict__ wsB,
               const float* __restrict__ csum,
               unsigned* __restrict__ oenc) {
    __shared__ alignas(16) unsigned short xb[8][256]; // 8 shifted bf16 copies
    __shared__ float xf[256];
    __shared__ float cps[32], cpq[32];                // exclusive chunk prefixes
    __shared__ float2 stats[W_BLK];                   // (mu, 1/(std*L))

    const int tid   = threadIdx.x;
    const int row   = blockIdx.x >> 5;
    const int chunk = blockIdx.x & 31;
    const int T0    = chunk * W_BLK;

    // ---- stage x chunk (255 elems) as fp32 + 8 shifted bf16 copies ----
    if (tid < 255) {
        int g = T0 + tid;
        float v = (g < T_LEN) ? x[row * T_LEN + g] : 0.f;
        xf[tid] = v;
        unsigned short b = f2bf(v);
        #pragma unroll
        for (int c = 0; c < 8; ++c) {
            int i = tid - c;
            if (i >= 0) xb[c][i] = b;                 // copy_c[i] = chunk[i+c]
        }
    } else {
        xf[255] = 0.f;
    }
    __syncthreads();

    // ---- per-8 chunk partial sums + 32-lane shuffle scan (wave 0) ----
    if (tid < 32) {
        float s = 0.f, q = 0.f;
        #pragma unroll
        for (int i = 0; i < 8; ++i) { float v = xf[tid * 8 + i]; s += v; q += v * v; }
        float s0 = s, q0 = q;
        #pragma unroll
        for (int off = 1; off < 32; off <<= 1) {
            float s2 = __shfl_up(s, off);
            float q2 = __shfl_up(q, off);
            if (tid >= off) { s += s2; q += q2; }
        }
        cps[tid] = s - s0;  cpq[tid] = q - q0;        // exclusive prefix
    }
    __syncthreads();

    // ---- per-window mean / inv(std*L) ----
    if (tid < W_BLK) {
        int w = tid;
        int c1 = w >> 3;
        float S1 = cps[c1], Q1 = cpq[c1];
        for (int i = c1 * 8; i < w; ++i) { float v = xf[i]; S1 += v; Q1 += v * v; }
        int e = w + L_LEN;
        int c2 = e >> 3;
        float S2 = cps[c2], Q2 = cpq[c2];
        for (int i = c2 * 8; i < e; ++i) { float v = xf[i]; S2 += v; Q2 += v * v; }
        float mu  = (S2 - S1) * (1.f / L_LEN);
        float ms  = (Q2 - Q1) * (1.f / L_LEN);
        float var = fmaxf(ms - mu * mu, 0.f);
        float sd  = sqrtf(var) + 1e-6f;
        stats[w]  = make_float2(mu, 1.f / (sd * (float)L_LEN));
    }

    // ---- B fragments -> registers (once per block) ----
    const int lane   = tid & 63;
    const int wv     = tid >> 6;
    const int nhalf  = wv & 1;
    const int mgroup = wv >> 1;

    short8 bfrag[4][4];
    float  cck[4];
    const short8* Bp = (const short8*)wsB;
    #pragma unroll
    for (int nt4 = 0; nt4 < 4; ++nt4) {
        int nt = nhalf * 4 + nt4;
        cck[nt4] = csum[nt * 16 + (lane & 15)];
        #pragma unroll
        for (int kt = 0; kt < 4; ++kt)
            bfrag[nt4][kt] = Bp[(nt * 4 + kt) * 64 + lane];
    }

    float4v acc[4][4];
    #pragma unroll
    for (int a = 0; a < 4; ++a)
        #pragma unroll
        for (int b = 0; b < 4; ++b)
            acc[a][b] = float4v{0.f, 0.f, 0.f, 0.f};

    // ---- MFMA K-loop: A[m][k] = copy_j[ 8*((lane&15)+(lane>>4)+4*kt) + jj ] ----
    const int abase = (lane & 15) + (lane >> 4);
    #pragma unroll
    for (int mi = 0; mi < 4; ++mi) {
        int j = mgroup * 4 + mi;
        #pragma unroll
        for (int kt = 0; kt < 4; ++kt) {
            short8 af = *(const short8*)&xb[j][8 * (abase + 4 * kt)];
            #pragma unroll
            for (int nt4 = 0; nt4 < 4; ++nt4)
                acc[mi][nt4] = __builtin_amdgcn_mfma_f32_16x16x32_bf16(
                    af, bfrag[nt4][kt], acc[mi][nt4], 0, 0, 0);
        }
    }
    __syncthreads();   // stats[] ready before epilogue

    // ---- epilogue: normalize, mask invalid windows, max ----
    float vmax[4] = {NEG_INF, NEG_INF, NEG_INF, NEG_INF};
    const int q4 = (lane >> 4) * 4;
    #pragma unroll
    for (int mi = 0; mi < 4; ++mi) {
        int j = mgroup * 4 + mi;
        #pragma unroll
        for (int r = 0; r < 4; ++r) {
            int wl = j + 8 * (q4 + r);                // D row -> window
            float2 st = stats[wl];
            bool valid = (T0 + wl) < NWIN;
            #pragma unroll
            for (int nt4 = 0; nt4 < 4; ++nt4) {
                float corr = (acc[mi][nt4][r] - st.x * cck[nt4]) * st.y;
                if (valid) vmax[nt4] = fmaxf(vmax[nt4], corr);
            }
        }
    }
    #pragma unroll
    for (int nt4 = 0; nt4 < 4; ++nt4) {
        float v = vmax[nt4];
        v = fmaxf(v, __shfl_xor(v, 16));
        v = fmaxf(v, __shfl_xor(v, 32));
        if (lane < 16 && v > NEG_INF) {
            int ck = (nhalf * 4 + nt4) * 16 + lane;
            atomicMax(&oenc[row * CK + ck], enc_f(v));
        }
    }
}

__global__ void decode_out(float* __restrict__ out) {
    int i = blockIdx.x * 256 + threadIdx.x;
    unsigned e = ((unsigned*)out)[i];
    out[i] = dec_f(e);
}

extern "C" void kernel_launch(void* const* d_in, const int* in_sizes, int n_in,
                              void* d_out, int out_size, void* d_ws, size_t ws_size,
                              hipStream_t stream) {
    (void)in_sizes; (void)n_in; (void)out_size; (void)ws_size;
    const float* x  = (const float*)d_in[0];
    const float* sh = (const float*)d_in[1];
    unsigned short* wsB = (unsigned short*)d_ws;                 // 32 KB
    float* csum = (float*)((char*)d_ws + 32768);                 // 512 B
    unsigned* oenc = (unsigned*)d_out;

    prep_init<<<256, 128, 0, stream>>>(sh, wsB, csum, oenc);
    conv_main<<<256 * NCHUNK, 256, 0, stream>>>(x, wsB, csum, oenc);
    decode_out<<<128, 256, 0, stream>>>((float*)d_out);
}

// Round 3
// 95.322 us; speedup vs baseline: 1.2475x; 1.2475x over previous
//
#include <hip/hip_runtime.h>
#include <hip/hip_bf16.h>

typedef __attribute__((ext_vector_type(8))) short short8;
typedef __attribute__((ext_vector_type(4))) float float4v;

#define T_LEN 4096
#define L_LEN 128
#define NWIN  3969
#define CK    128
#define W_BLK 128
#define NCHUNK 32

// ws layout: [wsB 32KB][csum 512B]   (33 KB total — R1-proven safe)
#define CSUM_OFF  32768

__device__ __forceinline__ unsigned short f2bf(float f) {
    unsigned u = __float_as_uint(f);
    u += 0x7fffu + ((u >> 16) & 1u);          // RNE
    return (unsigned short)(u >> 16);
}
__device__ __forceinline__ float bf2f(unsigned short b) {
    return __uint_as_float(((unsigned)b) << 16);
}

// grid 256 x 128 threads: blocks 0..127 zero-init d_out (positive-float max
// floor); blocks 128..255 normalize shapelet ck and write B-swizzled bf16.
__global__ void prep_init(const float* __restrict__ sh,
                          unsigned short* __restrict__ wsB,
                          float* __restrict__ csum,
                          unsigned* __restrict__ oenc) {
    const int t = threadIdx.x;           // 128 threads
    if (blockIdx.x < 128) {
        oenc[blockIdx.x * 256 + t]       = 0u;   // +0.0f floor
        oenc[blockIdx.x * 256 + 128 + t] = 0u;
        return;
    }
    const int ck = blockIdx.x - 128;     // shapelet index 0..127
    const int l  = t;
    __shared__ float rs[2], rq[2], rc[2];
    const int lane = t & 63, wv = t >> 6;

    float v = sh[ck * L_LEN + l];
    float s = v, q = v * v;
    #pragma unroll
    for (int off = 32; off >= 1; off >>= 1) {
        s += __shfl_xor(s, off);
        q += __shfl_xor(q, off);
    }
    if (lane == 0) { rs[wv] = s; rq[wv] = q; }
    __syncthreads();
    float sm = rs[0] + rs[1], sq = rq[0] + rq[1];
    float mu  = sm * (1.f / L_LEN);
    float var = fmaxf(sq * (1.f / L_LEN) - mu * mu, 0.f);
    float inv = 1.f / (sqrtf(var) + 1e-6f);

    unsigned short b = f2bf((v - mu) * inv);
    // B-operand fragment order: lane' = qd*16 + n, 8 contiguous bf16
    const int nt = ck >> 4, n = ck & 15;
    const int kt = l >> 5, qd = (l >> 3) & 3, jj = l & 7;
    wsB[((((nt * 4 + kt) * 64) + qd * 16 + n) << 3) + jj] = b;

    float cv = bf2f(b);
    #pragma unroll
    for (int off = 32; off >= 1; off >>= 1) cv += __shfl_xor(cv, off);
    if (lane == 0) rc[wv] = cv;
    __syncthreads();
    if (t == 0) csum[ck] = rc[0] + rc[1];
}

// block = (row, chunk of 128 windows); 4 waves.
// wave w: nhalf = w&1 (64 shapelets), mgroup = w>>1 (4 m-tiles).
// m-tile j covers windows T0 + j + 8m -> A-frags are aligned ds_read_b128
// from shifted copy j.
__global__ __launch_bounds__(256, 4)
void conv_main(const float* __restrict__ x,
               const unsigned short* __restrict__ wsB,
               const float* __restrict__ csum,
               unsigned* __restrict__ oenc) {
    __shared__ alignas(16) unsigned short xb[8][256]; // 8 shifted bf16 copies
    __shared__ float PS[257], PQ[257];
    __shared__ float wts[4], wtq[4];
    __shared__ float2 st[W_BLK];
    __shared__ float wmax[4][64];

    const int tid   = threadIdx.x;
    const int row   = blockIdx.x >> 5;
    const int chunk = blockIdx.x & 31;
    const int T0    = (chunk < 31) ? chunk * W_BLK : (NWIN - W_BLK); // overlap

    // ---- stage chunk element tid (in-register) + 8 shifted bf16 copies ----
    float v = 0.f;
    if (tid < 255) {
        v = x[row * T_LEN + T0 + tid];
        unsigned short b = f2bf(v);
        #pragma unroll
        for (int c = 0; c < 8; ++c) {
            int i = tid - c;
            if (i >= 0) xb[c][i] = b;
        }
    }

    // ---- parallel scan of (v, v^2): wave-inclusive + wave offsets ----
    const int lane = tid & 63;
    const int wv   = tid >> 6;
    float s = v, q = v * v;
    #pragma unroll
    for (int off = 1; off < 64; off <<= 1) {
        float ts = __shfl_up(s, off);
        float tq = __shfl_up(q, off);
        if (lane >= off) { s += ts; q += tq; }
    }
    if (lane == 63) { wts[wv] = s; wtq[wv] = q; }
    __syncthreads();                       // xb + wave totals ready
    float os = 0.f, oq = 0.f;
    #pragma unroll
    for (int w = 0; w < 3; ++w) if (w < wv) { os += wts[w]; oq += wtq[w]; }
    PS[tid + 1] = os + s;                  // inclusive prefix of first tid+1 elems
    PQ[tid + 1] = oq + q;
    if (tid == 0) { PS[0] = 0.f; PQ[0] = 0.f; }
    __syncthreads();                       // PS/PQ ready

    if (tid < W_BLK) {
        float S  = PS[tid + L_LEN] - PS[tid];
        float Q  = PQ[tid + L_LEN] - PQ[tid];
        float mu = S * (1.f / L_LEN);
        float var = fmaxf(Q * (1.f / L_LEN) - mu * mu, 0.f);
        float sd  = sqrtf(var) + 1e-6f;
        st[tid] = make_float2(mu, 1.f / (sd * (float)L_LEN));
    }

    // ---- MFMA (independent of st; hides the st barrier) ----
    const int nhalf  = wv & 1;
    const int mgroup = wv >> 1;
    const int abase  = (lane & 15) + (lane >> 4);

    float cck[4];
    #pragma unroll
    for (int nt4 = 0; nt4 < 4; ++nt4)
        cck[nt4] = csum[(nhalf * 4 + nt4) * 16 + (lane & 15)];

    float4v acc[4][4];
    #pragma unroll
    for (int a = 0; a < 4; ++a)
        #pragma unroll
        for (int b = 0; b < 4; ++b)
            acc[a][b] = float4v{0.f, 0.f, 0.f, 0.f};

    const short8* Bp = (const short8*)wsB;
    #pragma unroll
    for (int kt = 0; kt < 4; ++kt) {
        short8 bq[4];                                  // streamed: 16 live regs
        #pragma unroll
        for (int nt4 = 0; nt4 < 4; ++nt4)
            bq[nt4] = Bp[((nhalf * 4 + nt4) * 4 + kt) * 64 + lane];
        #pragma unroll
        for (int mi = 0; mi < 4; ++mi) {
            int j = mgroup * 4 + mi;
            short8 af = *(const short8*)&xb[j][8 * (abase + 4 * kt)];
            #pragma unroll
            for (int nt4 = 0; nt4 < 4; ++nt4)
                acc[mi][nt4] = __builtin_amdgcn_mfma_f32_16x16x32_bf16(
                    af, bq[nt4], acc[mi][nt4], 0, 0, 0);
        }
    }
    __syncthreads();                       // st ready before epilogue

    // ---- epilogue: normalize + max ----
    float vmax[4] = {-1e30f, -1e30f, -1e30f, -1e30f};
    const int q4 = (lane >> 4) * 4;
    #pragma unroll
    for (int mi = 0; mi < 4; ++mi) {
        int j = mgroup * 4 + mi;
        #pragma unroll
        for (int r = 0; r < 4; ++r) {
            float2 s2 = st[j + 8 * (q4 + r)];
            #pragma unroll
            for (int nt4 = 0; nt4 < 4; ++nt4) {
                float corr = (acc[mi][nt4][r] - s2.x * cck[nt4]) * s2.y;
                vmax[nt4] = fmaxf(vmax[nt4], corr);
            }
        }
    }
    #pragma unroll
    for (int nt4 = 0; nt4 < 4; ++nt4) {
        float vx = vmax[nt4];
        vx = fmaxf(vx, __shfl_xor(vx, 16));
        vx = fmaxf(vx, __shfl_xor(vx, 32));
        if (lane < 16) wmax[wv][nt4 * 16 + lane] = vx;
    }
    __syncthreads();
    if (tid < 128) {
        int ck = tid;
        int nh = ck >> 6, idx = ck & 63;
        float vx = fmaxf(wmax[nh][idx], wmax[nh + 2][idx]);
        vx = fmaxf(vx, 0.f);   // outputs >=0 w.h.p.; keeps uint-max ordering
        atomicMax(&oenc[row * CK + ck], __float_as_uint(vx));
    }
}

extern "C" void kernel_launch(void* const* d_in, const int* in_sizes, int n_in,
                              void* d_out, int out_size, void* d_ws, size_t ws_size,
                              hipStream_t stream) {
    (void)in_sizes; (void)n_in; (void)out_size; (void)ws_size;
    const float* x  = (const float*)d_in[0];
    const float* sh = (const float*)d_in[1];
    unsigned short* wsB = (unsigned short*)d_ws;
    float* csum = (float*)((char*)d_ws + CSUM_OFF);
    unsigned* oenc = (unsigned*)d_out;   // positive-float bit patterns

    prep_init<<<256, 128, 0, stream>>>(sh, wsB, csum, oenc);
    conv_main<<<256 * NCHUNK, 256, 0, stream>>>(x, wsB, csum, oenc);
}